// Round 5
// baseline (446.120 us; speedup 1.0000x reference)
//
#include <hip/hip_runtime.h>
#include <math.h>

#define Y_ 1024
#define X_ 2048
#define YX_ (Y_*X_)
#define RAD_ 12
#define NT_ 25
#define ND_ 27
#define APC_ 15
#define PAD_ 16

struct W25 { float w[NT_]; };
struct D27 { float d[ND_]; };

// ---------------------------------------------------------------------------
// K1: Y-smooth (circular) of the 7 input channels, 16 output rows per thread.
//   z in [0,4] -> y channels; z in [5,6] -> symmetrized v on the fly.
// ---------------------------------------------------------------------------
__global__ __launch_bounds__(256) void ksmooth_y7(
    const float* __restrict__ yin, const float* __restrict__ vin,
    float* __restrict__ out, W25 W)
{
  const int z  = blockIdx.z;
  const int y0 = blockIdx.y * 16;
  const int xo = (blockIdx.x * 256 + threadIdx.x) * 4;

  float4 acc[16];
#pragma unroll
  for (int j = 0; j < 16; ++j) acc[j] = make_float4(0.f, 0.f, 0.f, 0.f);

#pragma unroll
  for (int t = 0; t < 40; ++t) {
    const int r = (y0 - RAD_ + t + Y_) & (Y_ - 1);
    float4 val;
    if (z < 5) {
      val = *(const float4*)(yin + z * YX_ + r * X_ + xo);
    } else {
      const int   c   = z - 5;
      const float sgn = (c == 0) ? -1.f : 1.f;
      float4 a = *(const float4*)(vin + c * YX_ + r * X_ + xo);
      float4 b = *(const float4*)(vin + c * YX_ + (Y_ - 1 - r) * X_ + xo);
      val.x = 0.5f * (a.x + sgn * b.x);
      val.y = 0.5f * (a.y + sgn * b.y);
      val.z = 0.5f * (a.z + sgn * b.z);
      val.w = 0.5f * (a.w + sgn * b.w);
    }
#pragma unroll
    for (int j = 0; j < 16; ++j) {
      const int k = t - j;
      if (k >= 0 && k < NT_) {
        const float wk = W.w[k];
        acc[j].x += wk * val.x; acc[j].y += wk * val.y;
        acc[j].z += wk * val.z; acc[j].w += wk * val.w;
      }
    }
  }
#pragma unroll
  for (int j = 0; j < 16; ++j)
    *(float4*)(out + z * YX_ + (y0 + j) * X_ + xo) = acc[j];
}

// ---------------------------------------------------------------------------
// K2: LDS-staged fused X-smooth + gradient + pointwise algebra + AP-cut.
// One block per (row yy, half-row h). Per channel: ping-pong stage rows
// y-1,y,y+1 segment [xb-16, xb+1040) into LDS (coalesced), then compute
//   dX_j = sum_k D[k] * gY[y][x0-13+j+k]          (27-tap derivative kernel)
//   dY_j = sum_k W[k] * 0.5*(gY[y+1]-gY[y-1])[x0-12+j+k]
// straight from LDS with interleaved FMA (no register windows). dX/dY fold
// per-channel into adv[c] = v0*dY + v1*dX; only c=5,6 keep raw dX/dY.
// Identity valid for x in [13,2034] which covers the unmasked [15,2032];
// masked outputs are computed from (finite) garbage and multiplied by 0.
// ---------------------------------------------------------------------------
__global__ __launch_bounds__(256) void kgrad_lds(
    const float* __restrict__ gY,    // 7ch y-smoothed (has 16-float pad before)
    const float* __restrict__ yin,   // raw y, 5ch
    const float* __restrict__ vin,   // raw v, 2ch
    float* __restrict__ outB,        // 5ch pre-postprocess
    W25 W, D27 D)
{
  __shared__ float lds[2][3][1060];
  const int tid = threadIdx.x;
  const int yy  = blockIdx.y;
  const int xb  = blockIdx.x * 1024;
  const int x0  = xb + 4 * tid;
  const int yu  = (yy + 1) & (Y_ - 1);
  const int yd  = (yy - 1) & (Y_ - 1);

  // symmetrized raw v at this row (held across the channel loop)
  float v0[4], v1[4];
  {
    float4 a = *(const float4*)(vin + 0 * YX_ + yy * X_ + x0);
    float4 b = *(const float4*)(vin + 0 * YX_ + (Y_ - 1 - yy) * X_ + x0);
    float4 c = *(const float4*)(vin + 1 * YX_ + yy * X_ + x0);
    float4 d = *(const float4*)(vin + 1 * YX_ + (Y_ - 1 - yy) * X_ + x0);
    v0[0] = 0.5f*(a.x-b.x); v0[1] = 0.5f*(a.y-b.y);
    v0[2] = 0.5f*(a.z-b.z); v0[3] = 0.5f*(a.w-b.w);
    v1[0] = 0.5f*(c.x+d.x); v1[1] = 0.5f*(c.y+d.y);
    v1[2] = 0.5f*(c.z+d.z); v1[3] = 0.5f*(c.w+d.w);
  }

  auto STAGE = [&](int c, int b) {
    const float* pd = gY + c * YX_ + yd * X_ + xb - 16;
    const float* pc = gY + c * YX_ + yy * X_ + xb - 16;
    const float* pu = gY + c * YX_ + yu * X_ + xb - 16;
    *(float4*)&lds[b][0][4*tid] = *(const float4*)(pd + 4*tid);
    *(float4*)&lds[b][1][4*tid] = *(const float4*)(pc + 4*tid);
    *(float4*)&lds[b][2][4*tid] = *(const float4*)(pu + 4*tid);
    if (tid < 8) {
      *(float4*)&lds[b][0][1024 + 4*tid] = *(const float4*)(pd + 1024 + 4*tid);
      *(float4*)&lds[b][1][1024 + 4*tid] = *(const float4*)(pc + 1024 + 4*tid);
      *(float4*)&lds[b][2][1024 + 4*tid] = *(const float4*)(pu + 1024 + 4*tid);
    }
  };

  auto CONV = [&](int b, float aX[4], float aY[4]) {
#pragma unroll
    for (int j = 0; j < 4; ++j) { aX[j] = 0.f; aY[j] = 0.f; }
#pragma unroll
    for (int i = 0; i < 9; ++i) {
      const float4 ch = *(const float4*)&lds[b][1][4*tid + 4*i];
      const float cv[4] = {ch.x, ch.y, ch.z, ch.w};
#pragma unroll
      for (int e = 0; e < 4; ++e)
#pragma unroll
        for (int j = 0; j < 4; ++j) {
          const int k = 4*i + e - 3 - j;       // compile-time
          if (k >= 0 && k < ND_) aX[j] += D.d[k] * cv[e];
        }
    }
#pragma unroll
    for (int i = 0; i < 7; ++i) {
      const float4 u = *(const float4*)&lds[b][2][4*tid + 4 + 4*i];
      const float4 d = *(const float4*)&lds[b][0][4*tid + 4 + 4*i];
      const float dv[4] = {0.5f*(u.x-d.x), 0.5f*(u.y-d.y),
                           0.5f*(u.z-d.z), 0.5f*(u.w-d.w)};
#pragma unroll
      for (int e = 0; e < 4; ++e)
#pragma unroll
        for (int j = 0; j < 4; ++j) {
          const int k = 4*i + e - j;           // compile-time
          if (k >= 0 && k < NT_) aY[j] += W.w[k] * dv[e];
        }
    }
  };

  float adv[5][4], dX5[4], dY5[4], dX6[4], dY6[4];

  STAGE(0, 0);
  __syncthreads();
#pragma unroll
  for (int c = 0; c < 7; ++c) {
    if (c < 6) STAGE(c + 1, (c + 1) & 1);
    float aX[4], aY[4];
    CONV(c & 1, aX, aY);
#pragma unroll
    for (int j = 0; j < 4; ++j) {
      if (c < 5)        adv[c][j] = v0[j] * aY[j] + v1[j] * aX[j];
      else if (c == 5) { dX5[j] = aX[j]; dY5[j] = aY[j]; }
      else             { dX6[j] = aX[j]; dY6[j] = aY[j]; }
    }
    __syncthreads();
  }

  // raw fields + algebra
  float rm[5][4];
#pragma unroll
  for (int zc = 0; zc < 5; ++zc) {
    float4 t = *(const float4*)(yin + zc * YX_ + yy * X_ + x0);
    rm[zc][0] = t.x; rm[zc][1] = t.y; rm[zc][2] = t.z; rm[zc][3] = t.w;
  }

  float o[5][4];
#pragma unroll
  for (int j = 0; j < 4; ++j) {
    const float m00r = rm[0][j], m01r = rm[1][j], m10r = rm[2][j], m11r = rm[3][j];
    const float sr   = rm[4][j];

    const float w_  = -0.5f * (dX5[j] - dY6[j]);   // vorticity O[0][1]
    const float trE = dY5[j] + dX6[j];
    const float trm = m00r + m11r;

    const float lhs00 = adv[0][j] + w_ * (m10r + m01r);
    const float lhs01 = adv[1][j] + w_ * (m11r - m00r);
    const float lhs10 = adv[2][j] + w_ * (m11r - m00r);
    const float lhs11 = adv[3][j] - w_ * (m01r + m10r);

    const float f  = -(0.11f - 0.099f * sr)
                   + (0.767f + 0.055f * sr) * trE
                   + (0.732f - 0.59f  * sr) * trm;
    const float cd = (0.069f - 0.048f * sr) * trm;
    const float sd = -adv[4][j];

    const int   xg   = x0 + j;
    const float mask = (xg < APC_ || xg >= X_ - APC_) ? 0.f : 1.f;
    o[0][j] = mask * (f * m00r + cd - lhs00);
    o[1][j] = mask * (f * m01r      - lhs01);
    o[2][j] = mask * (f * m10r      - lhs10);
    o[3][j] = mask * (f * m11r      - lhs11);
    o[4][j] = mask * sd;
  }
#pragma unroll
  for (int zc = 0; zc < 5; ++zc)
    *(float4*)(outB + zc * YX_ + yy * X_ + x0) =
        make_float4(o[zc][0], o[zc][1], o[zc][2], o[zc][3]);
}

// ---------------------------------------------------------------------------
// K3a: LDS-staged X-smooth of 5ch (edge-replicate == zero-pad since the
// masked AP columns of B are exactly zero). One block per (row, half, ch).
// ---------------------------------------------------------------------------
__global__ __launch_bounds__(256) void kxs_lds(
    const float* __restrict__ B, float* __restrict__ C, W25 W)
{
  __shared__ float lds[1060];
  const int tid = threadIdx.x;
  const int z   = blockIdx.z;
  const int yy  = blockIdx.y;
  const int xb  = blockIdx.x * 1024;
  const float* row = B + z * YX_ + yy * X_ + xb - 16;

  {
    const int gx = xb - 16 + 4 * tid;
    float4 v = (gx >= 0 && gx < X_) ? *(const float4*)(row + 4 * tid)
                                    : make_float4(0.f, 0.f, 0.f, 0.f);
    *(float4*)&lds[4 * tid] = v;
    if (tid < 8) {
      const int gx2 = gx + 1024;
      float4 v2 = (gx2 >= 0 && gx2 < X_) ? *(const float4*)(row + 1024 + 4 * tid)
                                         : make_float4(0.f, 0.f, 0.f, 0.f);
      *(float4*)&lds[1024 + 4 * tid] = v2;
    }
  }
  __syncthreads();

  float a[4] = {0.f, 0.f, 0.f, 0.f};
#pragma unroll
  for (int i = 0; i < 7; ++i) {
    const float4 ch = *(const float4*)&lds[4*tid + 4 + 4*i];
    const float cv[4] = {ch.x, ch.y, ch.z, ch.w};
#pragma unroll
    for (int e = 0; e < 4; ++e)
#pragma unroll
      for (int j = 0; j < 4; ++j) {
        const int k = 4*i + e - j;             // compile-time
        if (k >= 0 && k < NT_) a[j] += W.w[k] * cv[e];
      }
  }
  *(float4*)(C + z * YX_ + yy * X_ + xb + 4 * tid) =
      make_float4(a[0], a[1], a[2], a[3]);
}

// ---------------------------------------------------------------------------
// K3b: Y-smooth (circular) of 5ch, 16 output rows per thread (streaming).
// ---------------------------------------------------------------------------
__global__ __launch_bounds__(256) void ksmooth_y5(
    const float* __restrict__ in, float* __restrict__ out, W25 W)
{
  const int z  = blockIdx.z;
  const int y0 = blockIdx.y * 16;
  const int xo = (blockIdx.x * 256 + threadIdx.x) * 4;

  float4 acc[16];
#pragma unroll
  for (int j = 0; j < 16; ++j) acc[j] = make_float4(0.f, 0.f, 0.f, 0.f);

#pragma unroll
  for (int t = 0; t < 40; ++t) {
    const int r = (y0 - RAD_ + t + Y_) & (Y_ - 1);
    float4 val = *(const float4*)(in + z * YX_ + r * X_ + xo);
#pragma unroll
    for (int j = 0; j < 16; ++j) {
      const int k = t - j;
      if (k >= 0 && k < NT_) {
        const float wk = W.w[k];
        acc[j].x += wk * val.x; acc[j].y += wk * val.y;
        acc[j].z += wk * val.z; acc[j].w += wk * val.w;
      }
    }
  }
#pragma unroll
  for (int j = 0; j < 16; ++j)
    *(float4*)(out + z * YX_ + (y0 + j) * X_ + xo) = acc[j];
}

// ---------------------------------------------------------------------------
extern "C" void kernel_launch(void* const* d_in, const int* in_sizes, int n_in,
                              void* d_out, int out_size, void* d_ws, size_t ws_size,
                              hipStream_t stream)
{
  const float* yin = (const float*)d_in[0];   // (5, 1024, 2048) f32
  const float* vin = (const float*)d_in[1];   // (2, 1024, 2048) f32
  float* out = (float*)d_out;                 // (5, 1024, 2048) f32

  // ws layout: [PAD_ floats][gY: 7ch][B: 5ch]; C aliases gY (dead after K2).
  float* gY = (float*)d_ws + PAD_;
  float* B  = gY + 7 * (size_t)YX_;
  float* C  = gY;

  W25 W; D27 D;
  double wd[NT_], s = 0.0;
  for (int i = 0; i < NT_; ++i) {
    const double x = i - RAD_;
    wd[i] = exp(-0.5 * (x / 3.0) * (x / 3.0));
    s += wd[i];
  }
  for (int i = 0; i < NT_; ++i) W.w[i] = (float)(wd[i] / s);
  for (int t = 0; t < ND_; ++t) {
    const double a = (t - 2 >= 0 && t - 2 < NT_) ? wd[t - 2] / s : 0.0;
    const double b = (t < NT_) ? wd[t] / s : 0.0;
    D.d[t] = (float)(0.5 * (a - b));
  }

  ksmooth_y7<<<dim3(2,   64, 7), 256, 0, stream>>>(yin, vin, gY, W);
  kgrad_lds <<<dim3(2, 1024   ), 256, 0, stream>>>(gY, yin, vin, B, W, D);
  kxs_lds   <<<dim3(2, 1024, 5), 256, 0, stream>>>(B, C, W);
  ksmooth_y5<<<dim3(2,   64, 5), 256, 0, stream>>>(C, out, W);
}

// Round 6
// 287.098 us; speedup vs baseline: 1.5539x; 1.5539x over previous
//
#include <hip/hip_runtime.h>
#include <math.h>

#define Y_ 1024
#define X_ 2048
#define YX_ (Y_*X_)
#define RAD_ 12
#define NT_ 25
#define ND_ 27
#define APC_ 15
#define PAD_ 16

struct W25 { float w[NT_]; };
struct D27 { float d[ND_]; };

// ---------------------------------------------------------------------------
// K1: Y-smooth (circular) of 7 input channels, 8 outputs/thread, loads
// batched 8-deep so ~8 loads are in flight before any consumption.
//   z<5: y channels.  z=5,6: symmetrized v computed on the fly.
// ---------------------------------------------------------------------------
__global__ __launch_bounds__(256) void ksmooth_y7b(
    const float* __restrict__ yin, const float* __restrict__ vin,
    float* __restrict__ out, W25 W)
{
  const int z  = blockIdx.z;
  const int y0 = blockIdx.y * 8;
  const int xo = (blockIdx.x * 256 + threadIdx.x) * 4;

  float4 acc[8];
#pragma unroll
  for (int j = 0; j < 8; ++j) acc[j] = make_float4(0.f, 0.f, 0.f, 0.f);

  if (z < 5) {
    const float* base = yin + z * YX_;
#pragma unroll
    for (int g = 0; g < 4; ++g) {
      float4 b[8];
#pragma unroll
      for (int i = 0; i < 8; ++i) {
        const int r = (y0 - RAD_ + 8*g + i + Y_) & (Y_ - 1);
        b[i] = *(const float4*)(base + r * X_ + xo);
      }
#pragma unroll
      for (int i = 0; i < 8; ++i) {
        const int t = 8*g + i;
#pragma unroll
        for (int j = 0; j < 8; ++j) {
          const int k = t - j;
          if (k >= 0 && k < NT_) {
            const float wk = W.w[k];
            acc[j].x += wk * b[i].x; acc[j].y += wk * b[i].y;
            acc[j].z += wk * b[i].z; acc[j].w += wk * b[i].w;
          }
        }
      }
    }
  } else {
    const int   c   = z - 5;
    const float sgn = (c == 0) ? -1.f : 1.f;
    const float* base = vin + c * YX_;
#pragma unroll
    for (int g = 0; g < 4; ++g) {
      float4 a8[8], b8[8];
#pragma unroll
      for (int i = 0; i < 8; ++i) {
        const int r = (y0 - RAD_ + 8*g + i + Y_) & (Y_ - 1);
        a8[i] = *(const float4*)(base + r * X_ + xo);
        b8[i] = *(const float4*)(base + (Y_ - 1 - r) * X_ + xo);
      }
#pragma unroll
      for (int i = 0; i < 8; ++i) {
        const int t = 8*g + i;
        float4 val;
        val.x = 0.5f * (a8[i].x + sgn * b8[i].x);
        val.y = 0.5f * (a8[i].y + sgn * b8[i].y);
        val.z = 0.5f * (a8[i].z + sgn * b8[i].z);
        val.w = 0.5f * (a8[i].w + sgn * b8[i].w);
#pragma unroll
        for (int j = 0; j < 8; ++j) {
          const int k = t - j;
          if (k >= 0 && k < NT_) {
            const float wk = W.w[k];
            acc[j].x += wk * val.x; acc[j].y += wk * val.y;
            acc[j].z += wk * val.z; acc[j].w += wk * val.w;
          }
        }
      }
    }
  }
#pragma unroll
  for (int j = 0; j < 8; ++j)
    *(float4*)(out + z * YX_ + (y0 + j) * X_ + xo) = acc[j];
}

// ---------------------------------------------------------------------------
// Per-channel derivative of the fully-smoothed field from the Y-smoothed one:
//   aX[j] = sum_k D[k] * gY[yy][x0-13+j+k-? ]  (27-tap, window x0-16..x0+19)
//   aY[j] = sum_k W[k] * 0.5*(gY[yu]-gY[yd])[x0-12+j+k]
// Validated tap math from round 4.
// ---------------------------------------------------------------------------
__device__ __forceinline__ void conv_ch(
    const float* __restrict__ rc, const float* __restrict__ ru,
    const float* __restrict__ rd, int x0, const W25& W, const D27& D,
    float aX[4], float aY[4])
{
  float wb[36];
#pragma unroll
  for (int i = 0; i < 9; ++i) {
    float4 t = *(const float4*)(rc + x0 - 16 + 4*i);
    wb[4*i+0] = t.x; wb[4*i+1] = t.y; wb[4*i+2] = t.z; wb[4*i+3] = t.w;
  }
#pragma unroll
  for (int j = 0; j < 4; ++j) {
    float s = 0.f;
#pragma unroll
    for (int t = 0; t < ND_; ++t) s += D.d[t] * wb[3 + j + t];
    aX[j] = s;
  }

  float db[28];
#pragma unroll
  for (int i = 0; i < 7; ++i) {
    float4 u = *(const float4*)(ru + x0 - 12 + 4*i);
    float4 d = *(const float4*)(rd + x0 - 12 + 4*i);
    db[4*i+0] = 0.5f * (u.x - d.x); db[4*i+1] = 0.5f * (u.y - d.y);
    db[4*i+2] = 0.5f * (u.z - d.z); db[4*i+3] = 0.5f * (u.w - d.w);
  }
#pragma unroll
  for (int j = 0; j < 4; ++j) {
    float s = 0.f;
#pragma unroll
    for (int t = 0; t < NT_; ++t) s += W.w[t] * db[j + t];
    aY[j] = s;
  }
}

// ---------------------------------------------------------------------------
// K2a: per-channel derivative + fold.  z in 0..4: F[z] = v0*dY_z + v1*dX_z.
// z==5: both v channels -> F[5] = w_ (vorticity), F[6] = trE.
// Masked columns produce finite garbage that kcombine discards.
// ---------------------------------------------------------------------------
__global__ __launch_bounds__(256) void kderiv(
    const float* __restrict__ gY, const float* __restrict__ vin,
    float* __restrict__ F, W25 W, D27 D)
{
  const int z  = blockIdx.z;            // 0..5, block-uniform
  const int yy = blockIdx.y;
  const int x0 = (blockIdx.x * 256 + threadIdx.x) * 4;
  const int yu = (yy + 1) & (Y_ - 1);
  const int yd = (yy - 1) & (Y_ - 1);

  if (z < 5) {
    float v0[4], v1[4];
    {
      float4 a = *(const float4*)(vin + 0 * YX_ + yy * X_ + x0);
      float4 b = *(const float4*)(vin + 0 * YX_ + (Y_ - 1 - yy) * X_ + x0);
      float4 c = *(const float4*)(vin + 1 * YX_ + yy * X_ + x0);
      float4 d = *(const float4*)(vin + 1 * YX_ + (Y_ - 1 - yy) * X_ + x0);
      v0[0] = 0.5f*(a.x-b.x); v0[1] = 0.5f*(a.y-b.y);
      v0[2] = 0.5f*(a.z-b.z); v0[3] = 0.5f*(a.w-b.w);
      v1[0] = 0.5f*(c.x+d.x); v1[1] = 0.5f*(c.y+d.y);
      v1[2] = 0.5f*(c.z+d.z); v1[3] = 0.5f*(c.w+d.w);
    }
    float aX[4], aY[4];
    conv_ch(gY + z*YX_ + yy*X_, gY + z*YX_ + yu*X_, gY + z*YX_ + yd*X_,
            x0, W, D, aX, aY);
    *(float4*)(F + z * YX_ + yy * X_ + x0) =
        make_float4(v0[0]*aY[0] + v1[0]*aX[0], v0[1]*aY[1] + v1[1]*aX[1],
                    v0[2]*aY[2] + v1[2]*aX[2], v0[3]*aY[3] + v1[3]*aX[3]);
  } else {
    float aX5[4], aY5[4], aX6[4], aY6[4];
    conv_ch(gY + 5*YX_ + yy*X_, gY + 5*YX_ + yu*X_, gY + 5*YX_ + yd*X_,
            x0, W, D, aX5, aY5);
    conv_ch(gY + 6*YX_ + yy*X_, gY + 6*YX_ + yu*X_, gY + 6*YX_ + yd*X_,
            x0, W, D, aX6, aY6);
    // w_ = -0.5*(dX(v0) - dY(v1));  trE = dY(v0) + dX(v1)
    *(float4*)(F + 5 * YX_ + yy * X_ + x0) =
        make_float4(-0.5f*(aX5[0]-aY6[0]), -0.5f*(aX5[1]-aY6[1]),
                    -0.5f*(aX5[2]-aY6[2]), -0.5f*(aX5[3]-aY6[3]));
    *(float4*)(F + 6 * YX_ + yy * X_ + x0) =
        make_float4(aY5[0]+aX6[0], aY5[1]+aX6[1],
                    aY5[2]+aX6[2], aY5[3]+aX6[3]);
  }
}

// ---------------------------------------------------------------------------
// K2b: pointwise algebra + AP-cut.  Reads F[0..6] + raw y; writes B (aliases
// F[0..4] — each thread reads all its F values before writing, one thread
// per point, so the alias is safe).
// ---------------------------------------------------------------------------
__global__ __launch_bounds__(256) void kcombine(
    const float* __restrict__ F, const float* __restrict__ yin,
    float* __restrict__ B)
{
  const int yy = blockIdx.y;
  const int x0 = (blockIdx.x * 256 + threadIdx.x) * 4;

  if (x0 < RAD_ || x0 > X_ - PAD_) {
#pragma unroll
    for (int zc = 0; zc < 5; ++zc)
      *(float4*)(B + zc * YX_ + yy * X_ + x0) = make_float4(0.f,0.f,0.f,0.f);
    return;
  }

  float adv[5][4];
#pragma unroll
  for (int c = 0; c < 5; ++c) {
    float4 t = *(const float4*)(F + c * YX_ + yy * X_ + x0);
    adv[c][0] = t.x; adv[c][1] = t.y; adv[c][2] = t.z; adv[c][3] = t.w;
  }
  float4 wv  = *(const float4*)(F + 5 * YX_ + yy * X_ + x0);
  float4 tev = *(const float4*)(F + 6 * YX_ + yy * X_ + x0);
  const float wa[4]  = {wv.x, wv.y, wv.z, wv.w};
  const float tea[4] = {tev.x, tev.y, tev.z, tev.w};

  float rm[5][4];
#pragma unroll
  for (int zc = 0; zc < 5; ++zc) {
    float4 t = *(const float4*)(yin + zc * YX_ + yy * X_ + x0);
    rm[zc][0] = t.x; rm[zc][1] = t.y; rm[zc][2] = t.z; rm[zc][3] = t.w;
  }

  float o[5][4];
#pragma unroll
  for (int j = 0; j < 4; ++j) {
    const float m00r = rm[0][j], m01r = rm[1][j], m10r = rm[2][j], m11r = rm[3][j];
    const float sr   = rm[4][j];
    const float w_   = wa[j];
    const float trE  = tea[j];
    const float trm  = m00r + m11r;

    const float lhs00 = adv[0][j] + w_ * (m10r + m01r);
    const float lhs01 = adv[1][j] + w_ * (m11r - m00r);
    const float lhs10 = adv[2][j] + w_ * (m11r - m00r);
    const float lhs11 = adv[3][j] - w_ * (m01r + m10r);

    const float f  = -(0.11f - 0.099f * sr)
                   + (0.767f + 0.055f * sr) * trE
                   + (0.732f - 0.59f  * sr) * trm;
    const float cd = (0.069f - 0.048f * sr) * trm;
    const float sd = -adv[4][j];

    const int   xg   = x0 + j;
    const float mask = (xg < APC_ || xg >= X_ - APC_) ? 0.f : 1.f;
    o[0][j] = mask * (f * m00r + cd - lhs00);
    o[1][j] = mask * (f * m01r      - lhs01);
    o[2][j] = mask * (f * m10r      - lhs10);
    o[3][j] = mask * (f * m11r      - lhs11);
    o[4][j] = mask * sd;
  }
#pragma unroll
  for (int zc = 0; zc < 5; ++zc)
    *(float4*)(B + zc * YX_ + yy * X_ + x0) =
        make_float4(o[zc][0], o[zc][1], o[zc][2], o[zc][3]);
}

// ---------------------------------------------------------------------------
// K3a: X-smooth (edge-replicate) of 5ch, 1 float4/thread, staged buf[28]
// (validated round-1 pattern).
// ---------------------------------------------------------------------------
__global__ __launch_bounds__(256) void kxsmooth(
    const float* __restrict__ in, float* __restrict__ out, W25 W)
{
  const int z  = blockIdx.z;
  const int yy = blockIdx.y;
  const int x0 = (blockIdx.x * 256 + threadIdx.x) * 4;
  const float* row = in + z * YX_ + yy * X_;

  float buf[28];
  if (x0 >= RAD_ && x0 + 4 + RAD_ <= X_) {
#pragma unroll
    for (int i = 0; i < 7; ++i) {
      float4 t = *(const float4*)(row + x0 - RAD_ + 4 * i);
      buf[4*i+0] = t.x; buf[4*i+1] = t.y; buf[4*i+2] = t.z; buf[4*i+3] = t.w;
    }
  } else {
#pragma unroll
    for (int i = 0; i < 28; ++i) {
      int xx = x0 - RAD_ + i;
      xx = xx < 0 ? 0 : (xx > X_ - 1 ? X_ - 1 : xx);
      buf[i] = row[xx];
    }
  }
  float a0 = 0.f, a1 = 0.f, a2 = 0.f, a3 = 0.f;
#pragma unroll
  for (int t = 0; t < NT_; ++t) {
    const float wk = W.w[t];
    a0 += wk * buf[t + 0];
    a1 += wk * buf[t + 1];
    a2 += wk * buf[t + 2];
    a3 += wk * buf[t + 3];
  }
  *(float4*)(out + z * YX_ + yy * X_ + x0) = make_float4(a0, a1, a2, a3);
}

// ---------------------------------------------------------------------------
// K3b: Y-smooth (circular) of 5ch, 8 outputs/thread, 8-deep load batches.
// ---------------------------------------------------------------------------
__global__ __launch_bounds__(256) void ksmooth_y5b(
    const float* __restrict__ in, float* __restrict__ out, W25 W)
{
  const int z  = blockIdx.z;
  const int y0 = blockIdx.y * 8;
  const int xo = (blockIdx.x * 256 + threadIdx.x) * 4;
  const float* base = in + z * YX_;

  float4 acc[8];
#pragma unroll
  for (int j = 0; j < 8; ++j) acc[j] = make_float4(0.f, 0.f, 0.f, 0.f);

#pragma unroll
  for (int g = 0; g < 4; ++g) {
    float4 b[8];
#pragma unroll
    for (int i = 0; i < 8; ++i) {
      const int r = (y0 - RAD_ + 8*g + i + Y_) & (Y_ - 1);
      b[i] = *(const float4*)(base + r * X_ + xo);
    }
#pragma unroll
    for (int i = 0; i < 8; ++i) {
      const int t = 8*g + i;
#pragma unroll
      for (int j = 0; j < 8; ++j) {
        const int k = t - j;
        if (k >= 0 && k < NT_) {
          const float wk = W.w[k];
          acc[j].x += wk * b[i].x; acc[j].y += wk * b[i].y;
          acc[j].z += wk * b[i].z; acc[j].w += wk * b[i].w;
        }
      }
    }
  }
#pragma unroll
  for (int j = 0; j < 8; ++j)
    *(float4*)(out + z * YX_ + (y0 + j) * X_ + xo) = acc[j];
}

// ---------------------------------------------------------------------------
extern "C" void kernel_launch(void* const* d_in, const int* in_sizes, int n_in,
                              void* d_out, int out_size, void* d_ws, size_t ws_size,
                              hipStream_t stream)
{
  const float* yin = (const float*)d_in[0];   // (5, 1024, 2048) f32
  const float* vin = (const float*)d_in[1];   // (2, 1024, 2048) f32
  float* out = (float*)d_out;                 // (5, 1024, 2048) f32

  // ws layout: [PAD_][gY: 7ch][F: 7ch]  (14ch total = proven budget).
  // B aliases F[0..4] (kcombine reads-then-writes pointwise, safe).
  // C aliases gY (dead after kderiv).
  float* gY = (float*)d_ws + PAD_;
  float* F  = gY + 7 * (size_t)YX_;
  float* B  = F;
  float* C  = gY;

  W25 W; D27 D;
  double wd[NT_], s = 0.0;
  for (int i = 0; i < NT_; ++i) {
    const double x = i - RAD_;
    wd[i] = exp(-0.5 * (x / 3.0) * (x / 3.0));
    s += wd[i];
  }
  for (int i = 0; i < NT_; ++i) W.w[i] = (float)(wd[i] / s);
  for (int t = 0; t < ND_; ++t) {
    const double a = (t - 2 >= 0 && t - 2 < NT_) ? wd[t - 2] / s : 0.0;
    const double b = (t < NT_) ? wd[t] / s : 0.0;
    D.d[t] = (float)(0.5 * (a - b));
  }

  ksmooth_y7b<<<dim3(2, 128, 7), 256, 0, stream>>>(yin, vin, gY, W);
  kderiv     <<<dim3(2, 1024, 6), 256, 0, stream>>>(gY, vin, F, W, D);
  kcombine   <<<dim3(2, 1024   ), 256, 0, stream>>>(F, yin, B);
  kxsmooth   <<<dim3(2, 1024, 5), 256, 0, stream>>>(B, C, W);
  ksmooth_y5b<<<dim3(2, 128, 5), 256, 0, stream>>>(C, out, W);
}

// Round 7
// 251.751 us; speedup vs baseline: 1.7721x; 1.1404x over previous
//
#include <hip/hip_runtime.h>
#include <math.h>

#define Y_ 1024
#define X_ 2048
#define YX_ (Y_*X_)
#define RAD_ 12
#define NT_ 25
#define ND_ 27
#define APC_ 15
#define PAD_ 16

struct W25 { float w[NT_]; };
struct D27 { float d[ND_]; };

// W-conv (25-tap) of window wb[36] (wb[i] = row[x0-16+i]) at outputs j=0..3:
//   wc[j] = sum_t W[t] * row[x0-12+j+t] = sum_t W[t]*wb[4+j+t]
// D-conv (27-tap):  dc[j] = sum_t D[t] * wb[3+j+t]        (validated r4)
__device__ __forceinline__ void wconv4(const float wb[36], const W25& W, float wc[4]) {
#pragma unroll
  for (int j = 0; j < 4; ++j) {
    float s = 0.f;
#pragma unroll
    for (int t = 0; t < NT_; ++t) s += W.w[t] * wb[4 + j + t];
    wc[j] = s;
  }
}
__device__ __forceinline__ void dconv4(const float wb[36], const D27& D, float dc[4]) {
#pragma unroll
  for (int j = 0; j < 4; ++j) {
    float s = 0.f;
#pragma unroll
    for (int t = 0; t < ND_; ++t) s += D.d[t] * wb[3 + j + t];
    dc[j] = s;
  }
}
__device__ __forceinline__ void load9(float wb[36], const float* p) {
#pragma unroll
  for (int i = 0; i < 9; ++i) {
    float4 t = *(const float4*)(p + 4 * i);
    wb[4*i+0] = t.x; wb[4*i+1] = t.y; wb[4*i+2] = t.z; wb[4*i+3] = t.w;
  }
}

// ---------------------------------------------------------------------------
// K1: Y-smooth (circular) of 7 channels, 16 rows/thread, 10-deep load
// batches, XCD-swizzled so each XCD owns contiguous y-chunks.
// ---------------------------------------------------------------------------
__global__ __launch_bounds__(256) void ksmooth_y7c(
    const float* __restrict__ yin, const float* __restrict__ vin,
    float* __restrict__ out, W25 W)
{
  const int id = blockIdx.x;                  // nwg = 2*64*7 = 896
  const int w  = (id & 7) * 112 + (id >> 3);  // bijective XCD swizzle
  const int yg = w % 64, xh = (w / 64) & 1, z = w / 128;
  const int y0 = yg * 16;
  const int xo = xh * 1024 + threadIdx.x * 4;

  float4 acc[16];
#pragma unroll
  for (int j = 0; j < 16; ++j) acc[j] = make_float4(0.f, 0.f, 0.f, 0.f);

  if (z < 5) {
    const float* base = yin + z * YX_;
#pragma unroll
    for (int g = 0; g < 4; ++g) {
      float4 b[10];
#pragma unroll
      for (int i = 0; i < 10; ++i) {
        const int r = (y0 - RAD_ + 10*g + i + Y_) & (Y_ - 1);
        b[i] = *(const float4*)(base + r * X_ + xo);
      }
#pragma unroll
      for (int i = 0; i < 10; ++i) {
        const int t = 10*g + i;
#pragma unroll
        for (int j = 0; j < 16; ++j) {
          const int k = t - j;
          if (k >= 0 && k < NT_) {
            const float wk = W.w[k];
            acc[j].x += wk * b[i].x; acc[j].y += wk * b[i].y;
            acc[j].z += wk * b[i].z; acc[j].w += wk * b[i].w;
          }
        }
      }
    }
  } else {
    const int   c   = z - 5;
    const float sgn = (c == 0) ? -1.f : 1.f;
    const float* base = vin + c * YX_;
#pragma unroll
    for (int g = 0; g < 8; ++g) {
      float4 a5[5], b5[5];
#pragma unroll
      for (int i = 0; i < 5; ++i) {
        const int r = (y0 - RAD_ + 5*g + i + Y_) & (Y_ - 1);
        a5[i] = *(const float4*)(base + r * X_ + xo);
        b5[i] = *(const float4*)(base + (Y_ - 1 - r) * X_ + xo);
      }
#pragma unroll
      for (int i = 0; i < 5; ++i) {
        const int t = 5*g + i;
        float4 val;
        val.x = 0.5f * (a5[i].x + sgn * b5[i].x);
        val.y = 0.5f * (a5[i].y + sgn * b5[i].y);
        val.z = 0.5f * (a5[i].z + sgn * b5[i].z);
        val.w = 0.5f * (a5[i].w + sgn * b5[i].w);
#pragma unroll
        for (int j = 0; j < 16; ++j) {
          const int k = t - j;
          if (k >= 0 && k < NT_) {
            const float wk = W.w[k];
            acc[j].x += wk * val.x; acc[j].y += wk * val.y;
            acc[j].z += wk * val.z; acc[j].w += wk * val.w;
          }
        }
      }
    }
  }
#pragma unroll
  for (int j = 0; j < 16; ++j)
    *(float4*)(out + z * YX_ + (y0 + j) * X_ + xo) = acc[j];
}

// ---------------------------------------------------------------------------
// K2: derivatives of the fully-smoothed fields from gY, 8 rows/thread,
// streaming wc-ring (1.25x y-redundancy), XCD-swizzled, folded outputs:
//   z<5 : F[z] = v0*dY_z + v1*dX_z        (advection term)
//   z=5 : F[5] = -0.5*(dX_c5 - dY_c6)     (vorticity w_)
//   z=6 : F[6] = dY_c5 + dX_c6            (trE)
// ---------------------------------------------------------------------------
__global__ __launch_bounds__(256) void kderiv2(
    const float* __restrict__ gY, const float* __restrict__ vin,
    float* __restrict__ F, W25 W, D27 D)
{
  const int id = blockIdx.x;                   // nwg = 2*128*7 = 1792
  const int w  = (id & 7) * 224 + (id >> 3);
  const int yg = w % 128, xh = (w / 128) & 1, z = w / 256;
  const int y0 = yg * 8;
  const int x0 = xh * 1024 + threadIdx.x * 4;

  float w2[4], w1[4], dcp[4];
#pragma unroll
  for (int j = 0; j < 4; ++j) { w2[j] = 0.f; w1[j] = 0.f; dcp[j] = 0.f; }

  if (z < 5) {
    const float* base = gY + z * YX_;
#pragma unroll
    for (int r = 0; r < 10; ++r) {
      const int ry = (y0 - 1 + r + Y_) & (Y_ - 1);
      float wb[36];
      load9(wb, base + ry * X_ + x0 - 16);
      float wc[4]; wconv4(wb, W, wc);
      float dc[4];
      if (r >= 1 && r <= 8) dconv4(wb, D, dc);
      else { dc[0]=dc[1]=dc[2]=dc[3]=0.f; }
      if (r >= 2) {
        const int t = r - 2, ty = y0 + t;
        float4 a  = *(const float4*)(vin + 0*YX_ + ty * X_ + x0);
        float4 bm = *(const float4*)(vin + 0*YX_ + (Y_-1-ty) * X_ + x0);
        float4 c  = *(const float4*)(vin + 1*YX_ + ty * X_ + x0);
        float4 dm = *(const float4*)(vin + 1*YX_ + (Y_-1-ty) * X_ + x0);
        const float v0[4] = {0.5f*(a.x-bm.x), 0.5f*(a.y-bm.y),
                             0.5f*(a.z-bm.z), 0.5f*(a.w-bm.w)};
        const float v1[4] = {0.5f*(c.x+dm.x), 0.5f*(c.y+dm.y),
                             0.5f*(c.z+dm.z), 0.5f*(c.w+dm.w)};
        float4 o;
        o.x = v0[0]*(0.5f*(wc[0]-w2[0])) + v1[0]*dcp[0];
        o.y = v0[1]*(0.5f*(wc[1]-w2[1])) + v1[1]*dcp[1];
        o.z = v0[2]*(0.5f*(wc[2]-w2[2])) + v1[2]*dcp[2];
        o.w = v0[3]*(0.5f*(wc[3]-w2[3])) + v1[3]*dcp[3];
        *(float4*)(F + z * YX_ + ty * X_ + x0) = o;
      }
#pragma unroll
      for (int j = 0; j < 4; ++j) { w2[j] = w1[j]; w1[j] = wc[j]; dcp[j] = dc[j]; }
    }
  } else if (z == 5) {
    // w_ = -0.5*(dX(ch5) - dY(ch6)): dc from ch5, wc-ring from ch6
    const float* b5 = gY + 5 * YX_;
    const float* b6 = gY + 6 * YX_;
#pragma unroll
    for (int r = 0; r < 10; ++r) {
      const int ry = (y0 - 1 + r + Y_) & (Y_ - 1);
      float wb[36];
      load9(wb, b6 + ry * X_ + x0 - 16);
      float wc[4]; wconv4(wb, W, wc);
      float dc[4];
      if (r >= 1 && r <= 8) {
        float wb5[36];
        load9(wb5, b5 + ry * X_ + x0 - 16);
        dconv4(wb5, D, dc);
      } else { dc[0]=dc[1]=dc[2]=dc[3]=0.f; }
      if (r >= 2) {
        const int t = r - 2, ty = y0 + t;
        float4 o;
        o.x = -0.5f*(dcp[0] - 0.5f*(wc[0]-w2[0]));
        o.y = -0.5f*(dcp[1] - 0.5f*(wc[1]-w2[1]));
        o.z = -0.5f*(dcp[2] - 0.5f*(wc[2]-w2[2]));
        o.w = -0.5f*(dcp[3] - 0.5f*(wc[3]-w2[3]));
        *(float4*)(F + 5 * YX_ + ty * X_ + x0) = o;
      }
#pragma unroll
      for (int j = 0; j < 4; ++j) { w2[j] = w1[j]; w1[j] = wc[j]; dcp[j] = dc[j]; }
    }
  } else {
    // trE = dY(ch5) + dX(ch6): wc-ring from ch5, dc from ch6
    const float* b5 = gY + 5 * YX_;
    const float* b6 = gY + 6 * YX_;
#pragma unroll
    for (int r = 0; r < 10; ++r) {
      const int ry = (y0 - 1 + r + Y_) & (Y_ - 1);
      float wb[36];
      load9(wb, b5 + ry * X_ + x0 - 16);
      float wc[4]; wconv4(wb, W, wc);
      float dc[4];
      if (r >= 1 && r <= 8) {
        float wb6[36];
        load9(wb6, b6 + ry * X_ + x0 - 16);
        dconv4(wb6, D, dc);
      } else { dc[0]=dc[1]=dc[2]=dc[3]=0.f; }
      if (r >= 2) {
        const int t = r - 2, ty = y0 + t;
        float4 o;
        o.x = dcp[0] + 0.5f*(wc[0]-w2[0]);
        o.y = dcp[1] + 0.5f*(wc[1]-w2[1]);
        o.z = dcp[2] + 0.5f*(wc[2]-w2[2]);
        o.w = dcp[3] + 0.5f*(wc[3]-w2[3]);
        *(float4*)(F + 6 * YX_ + ty * X_ + x0) = o;
      }
#pragma unroll
      for (int j = 0; j < 4; ++j) { w2[j] = w1[j]; w1[j] = wc[j]; dcp[j] = dc[j]; }
    }
  }
}

// ---------------------------------------------------------------------------
// K3: pointwise algebra + AP-cut. Reads F[0..6] + raw y; writes B (aliases
// F[0..4], read-before-write per point).
// ---------------------------------------------------------------------------
__global__ __launch_bounds__(256) void kcombine(
    const float* __restrict__ F, const float* __restrict__ yin,
    float* __restrict__ B)
{
  const int yy = blockIdx.y;
  const int x0 = (blockIdx.x * 256 + threadIdx.x) * 4;

  if (x0 < RAD_ || x0 > X_ - PAD_) {
#pragma unroll
    for (int zc = 0; zc < 5; ++zc)
      *(float4*)(B + zc * YX_ + yy * X_ + x0) = make_float4(0.f,0.f,0.f,0.f);
    return;
  }

  float adv[5][4];
#pragma unroll
  for (int c = 0; c < 5; ++c) {
    float4 t = *(const float4*)(F + c * YX_ + yy * X_ + x0);
    adv[c][0] = t.x; adv[c][1] = t.y; adv[c][2] = t.z; adv[c][3] = t.w;
  }
  float4 wv  = *(const float4*)(F + 5 * YX_ + yy * X_ + x0);
  float4 tev = *(const float4*)(F + 6 * YX_ + yy * X_ + x0);
  const float wa[4]  = {wv.x, wv.y, wv.z, wv.w};
  const float tea[4] = {tev.x, tev.y, tev.z, tev.w};

  float rm[5][4];
#pragma unroll
  for (int zc = 0; zc < 5; ++zc) {
    float4 t = *(const float4*)(yin + zc * YX_ + yy * X_ + x0);
    rm[zc][0] = t.x; rm[zc][1] = t.y; rm[zc][2] = t.z; rm[zc][3] = t.w;
  }

  float o[5][4];
#pragma unroll
  for (int j = 0; j < 4; ++j) {
    const float m00r = rm[0][j], m01r = rm[1][j], m10r = rm[2][j], m11r = rm[3][j];
    const float sr   = rm[4][j];
    const float w_   = wa[j];
    const float trE  = tea[j];
    const float trm  = m00r + m11r;

    const float lhs00 = adv[0][j] + w_ * (m10r + m01r);
    const float lhs01 = adv[1][j] + w_ * (m11r - m00r);
    const float lhs10 = adv[2][j] + w_ * (m11r - m00r);
    const float lhs11 = adv[3][j] - w_ * (m01r + m10r);

    const float f  = -(0.11f - 0.099f * sr)
                   + (0.767f + 0.055f * sr) * trE
                   + (0.732f - 0.59f  * sr) * trm;
    const float cd = (0.069f - 0.048f * sr) * trm;
    const float sd = -adv[4][j];

    const int   xg   = x0 + j;
    const float mask = (xg < APC_ || xg >= X_ - APC_) ? 0.f : 1.f;
    o[0][j] = mask * (f * m00r + cd - lhs00);
    o[1][j] = mask * (f * m01r      - lhs01);
    o[2][j] = mask * (f * m10r      - lhs10);
    o[3][j] = mask * (f * m11r      - lhs11);
    o[4][j] = mask * sd;
  }
#pragma unroll
  for (int zc = 0; zc < 5; ++zc)
    *(float4*)(B + zc * YX_ + yy * X_ + x0) =
        make_float4(o[zc][0], o[zc][1], o[zc][2], o[zc][3]);
}

// ---------------------------------------------------------------------------
// K4: X-smooth (edge-replicate) of 5ch, buf[28] pattern.
// ---------------------------------------------------------------------------
__global__ __launch_bounds__(256) void kxsmooth(
    const float* __restrict__ in, float* __restrict__ out, W25 W)
{
  const int z  = blockIdx.z;
  const int yy = blockIdx.y;
  const int x0 = (blockIdx.x * 256 + threadIdx.x) * 4;
  const float* row = in + z * YX_ + yy * X_;

  float buf[28];
  if (x0 >= RAD_ && x0 + 4 + RAD_ <= X_) {
#pragma unroll
    for (int i = 0; i < 7; ++i) {
      float4 t = *(const float4*)(row + x0 - RAD_ + 4 * i);
      buf[4*i+0] = t.x; buf[4*i+1] = t.y; buf[4*i+2] = t.z; buf[4*i+3] = t.w;
    }
  } else {
#pragma unroll
    for (int i = 0; i < 28; ++i) {
      int xx = x0 - RAD_ + i;
      xx = xx < 0 ? 0 : (xx > X_ - 1 ? X_ - 1 : xx);
      buf[i] = row[xx];
    }
  }
  float a0 = 0.f, a1 = 0.f, a2 = 0.f, a3 = 0.f;
#pragma unroll
  for (int t = 0; t < NT_; ++t) {
    const float wk = W.w[t];
    a0 += wk * buf[t + 0];
    a1 += wk * buf[t + 1];
    a2 += wk * buf[t + 2];
    a3 += wk * buf[t + 3];
  }
  *(float4*)(out + z * YX_ + yy * X_ + x0) = make_float4(a0, a1, a2, a3);
}

// ---------------------------------------------------------------------------
// K5: Y-smooth (circular) of 5ch, 16 rows/thread, batched, XCD-swizzled.
// ---------------------------------------------------------------------------
__global__ __launch_bounds__(256) void ksmooth_y5c(
    const float* __restrict__ in, float* __restrict__ out, W25 W)
{
  const int id = blockIdx.x;                  // nwg = 2*64*5 = 640
  const int w  = (id & 7) * 80 + (id >> 3);
  const int yg = w % 64, xh = (w / 64) & 1, z = w / 128;
  const int y0 = yg * 16;
  const int xo = xh * 1024 + threadIdx.x * 4;
  const float* base = in + z * YX_;

  float4 acc[16];
#pragma unroll
  for (int j = 0; j < 16; ++j) acc[j] = make_float4(0.f, 0.f, 0.f, 0.f);

#pragma unroll
  for (int g = 0; g < 4; ++g) {
    float4 b[10];
#pragma unroll
    for (int i = 0; i < 10; ++i) {
      const int r = (y0 - RAD_ + 10*g + i + Y_) & (Y_ - 1);
      b[i] = *(const float4*)(base + r * X_ + xo);
    }
#pragma unroll
    for (int i = 0; i < 10; ++i) {
      const int t = 10*g + i;
#pragma unroll
      for (int j = 0; j < 16; ++j) {
        const int k = t - j;
        if (k >= 0 && k < NT_) {
          const float wk = W.w[k];
          acc[j].x += wk * b[i].x; acc[j].y += wk * b[i].y;
          acc[j].z += wk * b[i].z; acc[j].w += wk * b[i].w;
        }
      }
    }
  }
#pragma unroll
  for (int j = 0; j < 16; ++j)
    *(float4*)(out + z * YX_ + (y0 + j) * X_ + xo) = acc[j];
}

// ---------------------------------------------------------------------------
extern "C" void kernel_launch(void* const* d_in, const int* in_sizes, int n_in,
                              void* d_out, int out_size, void* d_ws, size_t ws_size,
                              hipStream_t stream)
{
  const float* yin = (const float*)d_in[0];   // (5, 1024, 2048) f32
  const float* vin = (const float*)d_in[1];   // (2, 1024, 2048) f32
  float* out = (float*)d_out;                 // (5, 1024, 2048) f32

  // ws: [PAD_][gY: 7ch][F: 7ch].  B aliases F[0..4]; C aliases gY.
  float* gY = (float*)d_ws + PAD_;
  float* F  = gY + 7 * (size_t)YX_;
  float* B  = F;
  float* C  = gY;

  W25 W; D27 D;
  double wd[NT_], s = 0.0;
  for (int i = 0; i < NT_; ++i) {
    const double x = i - RAD_;
    wd[i] = exp(-0.5 * (x / 3.0) * (x / 3.0));
    s += wd[i];
  }
  for (int i = 0; i < NT_; ++i) W.w[i] = (float)(wd[i] / s);
  for (int t = 0; t < ND_; ++t) {
    const double a = (t - 2 >= 0 && t - 2 < NT_) ? wd[t - 2] / s : 0.0;
    const double b = (t < NT_) ? wd[t] / s : 0.0;
    D.d[t] = (float)(0.5 * (a - b));
  }

  ksmooth_y7c<<<896, 256, 0, stream>>>(yin, vin, gY, W);
  kderiv2    <<<1792, 256, 0, stream>>>(gY, vin, F, W, D);
  kcombine   <<<dim3(2, 1024), 256, 0, stream>>>(F, yin, B);
  kxsmooth   <<<dim3(2, 1024, 5), 256, 0, stream>>>(B, C, W);
  ksmooth_y5c<<<640, 256, 0, stream>>>(C, out, W);
}

// Round 8
// 224.334 us; speedup vs baseline: 1.9886x; 1.1222x over previous
//
#include <hip/hip_runtime.h>
#include <math.h>

#define Y_ 1024
#define X_ 2048
#define YX_ (Y_*X_)
#define RAD_ 12
#define NT_ 25
#define APC_ 15
#define PAD_ 16

struct W25 { float w[NT_]; };

__device__ __forceinline__ void load9(float wb[36], const float* p) {
#pragma unroll
  for (int i = 0; i < 9; ++i) {
    float4 t = *(const float4*)(p + 4 * i);
    wb[4*i+0] = t.x; wb[4*i+1] = t.y; wb[4*i+2] = t.z; wb[4*i+3] = t.w;
  }
}

// Per-channel derivatives of the fully-smoothed field from the Y-smoothed gY:
//   wc6[jj] = 25-tap X-smooth at x0-1+jj  (jj=0..5)  -> dX[j] = 0.5*(wc6[j+2]-wc6[j])
//   dY[j]   = 0.5*(conv25(row y+1) - conv25(row y-1)) at x0+j
// One reused window buffer to keep VGPR modest. Valid for unmasked x in [15,2032].
__device__ __forceinline__ void derivs_ch(
    const float* __restrict__ base, int yy, int yu, int yd, int x0,
    const W25& W, float dX[4], float dY[4])
{
  float wb[36];
  load9(wb, base + yy * X_ + x0 - 16);
  float wc6[6];
#pragma unroll
  for (int jj = 0; jj < 6; ++jj) {
    float s = 0.f;
#pragma unroll
    for (int t = 0; t < NT_; ++t) s += W.w[t] * wb[3 + jj + t];
    wc6[jj] = s;
  }
#pragma unroll
  for (int j = 0; j < 4; ++j) dX[j] = 0.5f * (wc6[j + 2] - wc6[j]);

  float au[4], ad[4];
  load9(wb, base + yu * X_ + x0 - 16);
#pragma unroll
  for (int j = 0; j < 4; ++j) {
    float s = 0.f;
#pragma unroll
    for (int t = 0; t < NT_; ++t) s += W.w[t] * wb[4 + j + t];
    au[j] = s;
  }
  load9(wb, base + yd * X_ + x0 - 16);
#pragma unroll
  for (int j = 0; j < 4; ++j) {
    float s = 0.f;
#pragma unroll
    for (int t = 0; t < NT_; ++t) s += W.w[t] * wb[4 + j + t];
    ad[j] = s;
  }
#pragma unroll
  for (int j = 0; j < 4; ++j) dY[j] = 0.5f * (au[j] - ad[j]);
}

// ---------------------------------------------------------------------------
// K1: Y-smooth (circular) of 7 channels, 16 rows/thread, 10-deep load
// batches, XCD-swizzled (unchanged from round 7).
// ---------------------------------------------------------------------------
__global__ __launch_bounds__(256) void ksmooth_y7c(
    const float* __restrict__ yin, const float* __restrict__ vin,
    float* __restrict__ out, W25 W)
{
  const int id = blockIdx.x;                  // nwg = 2*64*7 = 896
  const int w  = (id & 7) * 112 + (id >> 3);  // bijective XCD swizzle
  const int yg = w % 64, xh = (w / 64) & 1, z = w / 128;
  const int y0 = yg * 16;
  const int xo = xh * 1024 + threadIdx.x * 4;

  float4 acc[16];
#pragma unroll
  for (int j = 0; j < 16; ++j) acc[j] = make_float4(0.f, 0.f, 0.f, 0.f);

  if (z < 5) {
    const float* base = yin + z * YX_;
#pragma unroll
    for (int g = 0; g < 4; ++g) {
      float4 b[10];
#pragma unroll
      for (int i = 0; i < 10; ++i) {
        const int r = (y0 - RAD_ + 10*g + i + Y_) & (Y_ - 1);
        b[i] = *(const float4*)(base + r * X_ + xo);
      }
#pragma unroll
      for (int i = 0; i < 10; ++i) {
        const int t = 10*g + i;
#pragma unroll
        for (int j = 0; j < 16; ++j) {
          const int k = t - j;
          if (k >= 0 && k < NT_) {
            const float wk = W.w[k];
            acc[j].x += wk * b[i].x; acc[j].y += wk * b[i].y;
            acc[j].z += wk * b[i].z; acc[j].w += wk * b[i].w;
          }
        }
      }
    }
  } else {
    const int   c   = z - 5;
    const float sgn = (c == 0) ? -1.f : 1.f;
    const float* base = vin + c * YX_;
#pragma unroll
    for (int g = 0; g < 8; ++g) {
      float4 a5[5], b5[5];
#pragma unroll
      for (int i = 0; i < 5; ++i) {
        const int r = (y0 - RAD_ + 5*g + i + Y_) & (Y_ - 1);
        a5[i] = *(const float4*)(base + r * X_ + xo);
        b5[i] = *(const float4*)(base + (Y_ - 1 - r) * X_ + xo);
      }
#pragma unroll
      for (int i = 0; i < 5; ++i) {
        const int t = 5*g + i;
        float4 val;
        val.x = 0.5f * (a5[i].x + sgn * b5[i].x);
        val.y = 0.5f * (a5[i].y + sgn * b5[i].y);
        val.z = 0.5f * (a5[i].z + sgn * b5[i].z);
        val.w = 0.5f * (a5[i].w + sgn * b5[i].w);
#pragma unroll
        for (int j = 0; j < 16; ++j) {
          const int k = t - j;
          if (k >= 0 && k < NT_) {
            const float wk = W.w[k];
            acc[j].x += wk * val.x; acc[j].y += wk * val.y;
            acc[j].z += wk * val.z; acc[j].w += wk * val.w;
          }
        }
      }
    }
  }
#pragma unroll
  for (int j = 0; j < 16; ++j)
    *(float4*)(out + z * YX_ + (y0 + j) * X_ + xo) = acc[j];
}

// ---------------------------------------------------------------------------
// K2: fused derivatives + pointwise algebra + AP-cut. 1 output row/thread,
// all 7 channels in-register (w_, trE never touch HBM), XCD-swizzled.
// Writes the 5 pre-postprocess channels to B.
// ---------------------------------------------------------------------------
__global__ __launch_bounds__(256) void kfused(
    const float* __restrict__ gY,    // 7ch y-smoothed (16-float pad before)
    const float* __restrict__ yin,   // raw y, 5ch
    const float* __restrict__ vin,   // raw v, 2ch
    float* __restrict__ B,           // 5ch out
    W25 W)
{
  const int id = blockIdx.x;                   // nwg = 2048
  const int w  = (id & 7) * 256 + (id >> 3);   // XCD swizzle: contiguous bands
  const int yy = w & (Y_ - 1);
  const int xh = w >> 10;
  const int x0 = xh * 1024 + threadIdx.x * 4;

  if (x0 < RAD_ || x0 > X_ - PAD_) {           // fully-masked float4 groups
#pragma unroll
    for (int zc = 0; zc < 5; ++zc)
      *(float4*)(B + zc * YX_ + yy * X_ + x0) = make_float4(0.f,0.f,0.f,0.f);
    return;
  }

  const int yu = (yy + 1) & (Y_ - 1);
  const int yd = (yy - 1) & (Y_ - 1);

  // symmetrized raw v at this row
  float v0[4], v1[4];
  {
    float4 a = *(const float4*)(vin + 0 * YX_ + yy * X_ + x0);
    float4 b = *(const float4*)(vin + 0 * YX_ + (Y_ - 1 - yy) * X_ + x0);
    float4 c = *(const float4*)(vin + 1 * YX_ + yy * X_ + x0);
    float4 d = *(const float4*)(vin + 1 * YX_ + (Y_ - 1 - yy) * X_ + x0);
    v0[0] = 0.5f*(a.x-b.x); v0[1] = 0.5f*(a.y-b.y);
    v0[2] = 0.5f*(a.z-b.z); v0[3] = 0.5f*(a.w-b.w);
    v1[0] = 0.5f*(c.x+d.x); v1[1] = 0.5f*(c.y+d.y);
    v1[2] = 0.5f*(c.z+d.z); v1[3] = 0.5f*(c.w+d.w);
  }

  // velocity-derived fields first (all in registers)
  float w_[4], trE[4];
  {
    float dX5[4], dY5[4], dX6[4], dY6[4];
    derivs_ch(gY + 5 * YX_, yy, yu, yd, x0, W, dX5, dY5);
    derivs_ch(gY + 6 * YX_, yy, yu, yd, x0, W, dX6, dY6);
#pragma unroll
    for (int j = 0; j < 4; ++j) {
      w_[j]  = -0.5f * (dX5[j] - dY6[j]);      // vorticity O[0][1]
      trE[j] = dY5[j] + dX6[j];
    }
  }

  // advection folds for m (4ch) + s
  float acc[5][4];
#pragma unroll
  for (int c = 0; c < 5; ++c) {
    float dX[4], dY[4];
    derivs_ch(gY + c * YX_, yy, yu, yd, x0, W, dX, dY);
#pragma unroll
    for (int j = 0; j < 4; ++j) acc[c][j] = v0[j] * dY[j] + v1[j] * dX[j];
  }

  // raw fields + algebra (kcombine epilogue)
  float rm[5][4];
#pragma unroll
  for (int zc = 0; zc < 5; ++zc) {
    float4 t = *(const float4*)(yin + zc * YX_ + yy * X_ + x0);
    rm[zc][0] = t.x; rm[zc][1] = t.y; rm[zc][2] = t.z; rm[zc][3] = t.w;
  }

  float o[5][4];
#pragma unroll
  for (int j = 0; j < 4; ++j) {
    const float m00r = rm[0][j], m01r = rm[1][j], m10r = rm[2][j], m11r = rm[3][j];
    const float sr   = rm[4][j];
    const float wj   = w_[j];
    const float trm  = m00r + m11r;

    const float lhs00 = acc[0][j] + wj * (m10r + m01r);
    const float lhs01 = acc[1][j] + wj * (m11r - m00r);
    const float lhs10 = acc[2][j] + wj * (m11r - m00r);
    const float lhs11 = acc[3][j] - wj * (m01r + m10r);

    const float f  = -(0.11f - 0.099f * sr)
                   + (0.767f + 0.055f * sr) * trE[j]
                   + (0.732f - 0.59f  * sr) * trm;
    const float cd = (0.069f - 0.048f * sr) * trm;
    const float sd = -acc[4][j];

    const int   xg   = x0 + j;
    const float mask = (xg < APC_ || xg >= X_ - APC_) ? 0.f : 1.f;
    o[0][j] = mask * (f * m00r + cd - lhs00);
    o[1][j] = mask * (f * m01r      - lhs01);
    o[2][j] = mask * (f * m10r      - lhs10);
    o[3][j] = mask * (f * m11r      - lhs11);
    o[4][j] = mask * sd;
  }
#pragma unroll
  for (int zc = 0; zc < 5; ++zc)
    *(float4*)(B + zc * YX_ + yy * X_ + x0) =
        make_float4(o[zc][0], o[zc][1], o[zc][2], o[zc][3]);
}

// ---------------------------------------------------------------------------
// K3: X-smooth (edge-replicate) of 5ch, buf[28] pattern (unchanged).
// ---------------------------------------------------------------------------
__global__ __launch_bounds__(256) void kxsmooth(
    const float* __restrict__ in, float* __restrict__ out, W25 W)
{
  const int z  = blockIdx.z;
  const int yy = blockIdx.y;
  const int x0 = (blockIdx.x * 256 + threadIdx.x) * 4;
  const float* row = in + z * YX_ + yy * X_;

  float buf[28];
  if (x0 >= RAD_ && x0 + 4 + RAD_ <= X_) {
#pragma unroll
    for (int i = 0; i < 7; ++i) {
      float4 t = *(const float4*)(row + x0 - RAD_ + 4 * i);
      buf[4*i+0] = t.x; buf[4*i+1] = t.y; buf[4*i+2] = t.z; buf[4*i+3] = t.w;
    }
  } else {
#pragma unroll
    for (int i = 0; i < 28; ++i) {
      int xx = x0 - RAD_ + i;
      xx = xx < 0 ? 0 : (xx > X_ - 1 ? X_ - 1 : xx);
      buf[i] = row[xx];
    }
  }
  float a0 = 0.f, a1 = 0.f, a2 = 0.f, a3 = 0.f;
#pragma unroll
  for (int t = 0; t < NT_; ++t) {
    const float wk = W.w[t];
    a0 += wk * buf[t + 0];
    a1 += wk * buf[t + 1];
    a2 += wk * buf[t + 2];
    a3 += wk * buf[t + 3];
  }
  *(float4*)(out + z * YX_ + yy * X_ + x0) = make_float4(a0, a1, a2, a3);
}

// ---------------------------------------------------------------------------
// K4: Y-smooth (circular) of 5ch, 16 rows/thread, batched, XCD-swizzled
// (unchanged).
// ---------------------------------------------------------------------------
__global__ __launch_bounds__(256) void ksmooth_y5c(
    const float* __restrict__ in, float* __restrict__ out, W25 W)
{
  const int id = blockIdx.x;                  // nwg = 2*64*5 = 640
  const int w  = (id & 7) * 80 + (id >> 3);
  const int yg = w % 64, xh = (w / 64) & 1, z = w / 128;
  const int y0 = yg * 16;
  const int xo = xh * 1024 + threadIdx.x * 4;
  const float* base = in + z * YX_;

  float4 acc[16];
#pragma unroll
  for (int j = 0; j < 16; ++j) acc[j] = make_float4(0.f, 0.f, 0.f, 0.f);

#pragma unroll
  for (int g = 0; g < 4; ++g) {
    float4 b[10];
#pragma unroll
    for (int i = 0; i < 10; ++i) {
      const int r = (y0 - RAD_ + 10*g + i + Y_) & (Y_ - 1);
      b[i] = *(const float4*)(base + r * X_ + xo);
    }
#pragma unroll
    for (int i = 0; i < 10; ++i) {
      const int t = 10*g + i;
#pragma unroll
      for (int j = 0; j < 16; ++j) {
        const int k = t - j;
        if (k >= 0 && k < NT_) {
          const float wk = W.w[k];
          acc[j].x += wk * b[i].x; acc[j].y += wk * b[i].y;
          acc[j].z += wk * b[i].z; acc[j].w += wk * b[i].w;
        }
      }
    }
  }
#pragma unroll
  for (int j = 0; j < 16; ++j)
    *(float4*)(out + z * YX_ + (y0 + j) * X_ + xo) = acc[j];
}

// ---------------------------------------------------------------------------
extern "C" void kernel_launch(void* const* d_in, const int* in_sizes, int n_in,
                              void* d_out, int out_size, void* d_ws, size_t ws_size,
                              hipStream_t stream)
{
  const float* yin = (const float*)d_in[0];   // (5, 1024, 2048) f32
  const float* vin = (const float*)d_in[1];   // (2, 1024, 2048) f32
  float* out = (float*)d_out;                 // (5, 1024, 2048) f32

  // ws: [PAD_][gY: 7ch][B: 5ch].  C aliases gY (dead after kfused).
  float* gY = (float*)d_ws + PAD_;
  float* B  = gY + 7 * (size_t)YX_;
  float* C  = gY;

  W25 W;
  double wd[NT_], s = 0.0;
  for (int i = 0; i < NT_; ++i) {
    const double x = i - RAD_;
    wd[i] = exp(-0.5 * (x / 3.0) * (x / 3.0));
    s += wd[i];
  }
  for (int i = 0; i < NT_; ++i) W.w[i] = (float)(wd[i] / s);

  ksmooth_y7c<<<896,  256, 0, stream>>>(yin, vin, gY, W);
  kfused     <<<2048, 256, 0, stream>>>(gY, yin, vin, B, W);
  kxsmooth   <<<dim3(2, 1024, 5), 256, 0, stream>>>(B, C, W);
  ksmooth_y5c<<<640,  256, 0, stream>>>(C, out, W);
}